// Round 9
// baseline (128.092 us; speedup 1.0000x reference)
//
#include <hip/hip_runtime.h>
#include <hip/hip_bf16.h>
#include <cstdint>
#include <cmath>

#define BB 4
#define TT 2048
#define DD 512
#define RR 1024
#define MM (BB*RR)       // 4096
#define NBINS 13
#define LDXP (NBINS*DD)  // 6656

typedef __bf16 bf16;
typedef bf16 bf16x8 __attribute__((ext_vector_type(8)));
typedef bf16 bf16x2 __attribute__((ext_vector_type(2)));
typedef float f32x4 __attribute__((ext_vector_type(4)));

__device__ __forceinline__ float selu_f(float x) {
    const float sc = 1.0507009873554805f;
    const float aa = 1.6732632423543772f;
    return x > 0.0f ? sc * x : sc * aa * (expf(x) - 1.0f);
}

__device__ __forceinline__ void gload_lds16(const bf16* g, bf16* l) {
    __builtin_amdgcn_global_load_lds(
        (const __attribute__((address_space(1))) void*)g,
        (__attribute__((address_space(3))) void*)l, 16, 0, 0);
}

template<int N>
__device__ __forceinline__ void wait_vm() {
    if constexpr (N == 0)       asm volatile("s_waitcnt vmcnt(0)" ::: "memory");
    else if constexpr (N == 3)  asm volatile("s_waitcnt vmcnt(3)" ::: "memory");
    else if constexpr (N == 5)  asm volatile("s_waitcnt vmcnt(5)" ::: "memory");
    else if constexpr (N == 6)  asm volatile("s_waitcnt vmcnt(6)" ::: "memory");
    else if constexpr (N == 10) asm volatile("s_waitcnt vmcnt(10)" ::: "memory");
}

__device__ __forceinline__ void lgkm_fence() {
    asm volatile("s_waitcnt lgkmcnt(0)" ::: "memory");
    __builtin_amdgcn_sched_barrier(0);
}

// Stage a [ROWS][32] bf16 half-tile into LDS, swizzled: physical 16B slot p of
// row r holds logical slot p ^ ((r>>1)&3).  LDS dest linear (global_load_lds
// writes wave-base + lane*16); the source address carries the permutation.
// 256 threads; ROWS*4 slot-loads.
template<int ROWS>
__device__ __forceinline__ void stage_half(const bf16* __restrict__ src, int lda,
                                           bf16* dst, int tid) {
#pragma unroll
    for (int it = 0; it < ROWS / 64; ++it) {
        int idx = it * 256 + tid;
        int row = idx >> 2;                               // 4 slots of 16B per 64B row
        int col = ((idx & 3) ^ ((row >> 1) & 3)) * 8;
        bf16* wavebase = dst + (idx & ~63) * 8;           // wave-uniform base
        gload_lds16(src + (size_t)row * lda + col, wavebase);
    }
}

// Fragment read with the matching XOR.  16 lanes (rows r..r+15, same sl)
// spread over 8 distinct bank-quads -> 2-way (free).
__device__ __forceinline__ bf16x8 frd32(const bf16* half, int row, int sl) {
    int p = sl ^ ((row >> 1) & 3);
    return *(const bf16x8*)(half + row * 32 + p * 8);
}

// ---------------- fused prep: pool + weight transforms ----------------
template<int NB_, int KT>
__device__ __forceinline__ void w_row_body(const float* __restrict__ Wsrc,
                                           bf16* __restrict__ Wdst,
                                           float* ld, int n, int tid) {
    const float* src = Wsrc + (size_t)n * KT;
    for (int i = tid; i < KT; i += 256) ld[i] = src[i];
    __syncthreads();
    bf16* dst = Wdst + (size_t)n * KT;
    for (int i = tid; i < KT; i += 256) {
        int bin = i >> 9, d = i & 511;
        dst[i] = (bf16)ld[d * NB_ + bin];
    }
}

__device__ __forceinline__ void pool_body(const float* __restrict__ feats,
                                          const float* __restrict__ rois,
                                          bf16* __restrict__ Xp, int m, int tid) {
    int b = m >> 10;
    float s = rois[2 * m];
    float e = rois[2 * m + 1];
    float ext = 0.2f * (e - s);
    int d0 = tid * 2;
    bf16* orow = Xp + (size_t)m * LDXP + d0;
    const float* fb = feats + (size_t)b * TT * DD + d0;
#pragma unroll
    for (int j = 0; j < NBINS; ++j) {
        float pos;
        if (j < 2)       pos = (s - ext) + ((float)j + 0.5f) * ext;
        else if (j < 11) pos = s + (((float)(j - 2) + 0.5f) * (1.0f / 9.0f)) * (e - s);
        else             pos = (e - ext) + ((float)(j - 11) + 0.5f) * ext;
        pos = fminf(fmaxf(pos, 0.0f), (float)(TT - 1));
        float fl = floorf(pos);
        int lo = (int)fl;
        int hi = lo + 1; if (hi > TT - 1) hi = TT - 1;
        float w = pos - fl;
        float2 vlo = *(const float2*)(fb + (size_t)lo * DD);
        float2 vhi = *(const float2*)(fb + (size_t)hi * DD);
        bf16x2 o;
        o.x = (bf16)((1.0f - w) * vlo.x + w * vhi.x);
        o.y = (bf16)((1.0f - w) * vlo.y + w * vhi.y);
        *(bf16x2*)(orow + j * DD) = o;
    }
}

__global__ __launch_bounds__(256) void prep_all(
    const float* __restrict__ feats, const float* __restrict__ rois,
    const float* __restrict__ W_left, const float* __restrict__ W_inner,
    const float* __restrict__ W_roi,
    bf16* __restrict__ Xp, bf16* __restrict__ Wl, bf16* __restrict__ Wi,
    bf16* __restrict__ Wr)
{
    __shared__ float ld[4608];
    int bid = blockIdx.x, tid = threadIdx.x;
    if (bid < 4096) {
        pool_body(feats, rois, Xp, bid, tid);
    } else if (bid < 4608) {
        w_row_body<7, 3584>(W_left, Wl, ld, bid - 4096, tid);
    } else if (bid < 5120) {
        w_row_body<9, 4608>(W_inner, Wi, ld, bid - 4608, tid);
    } else {
        int i0 = (bid - 5120) * 1024 + tid * 4;
        float4 v = *(const float4*)(W_roi + i0);
        bf16* d = Wr + i0;
        d[0] = (bf16)v.x; d[1] = (bf16)v.y; d[2] = (bf16)v.z; d[3] = (bf16)v.w;
    }
}

// ---------------- GEMM bodies: multi-phase interleave ----------------
// BM=128, BN=64, BK=64; 256 threads = 4 waves (2x2), wave tile 64x32 (4x2).
// K-tile split into 2 column-halves staged independently (depth-3 halves with
// 2 buffers).  Phases: {gload issue | ds_read frags | counted vmcnt | barrier
// | lgkmcnt(0) | setprio MFMA | barrier}.  vmcnt never 0 in main loop.
//
// vmcnt bookkeeping (per thread; loads/half-stage: dual 5, single 3):
//   issue order ... (t,H0)@t-2, (t,H1)@t-1 P1, (t+1,H0)@t-1 Pend, (t+1,H1)@t P1,
//   (t+2,H0)@t Pmid.  Guard (t,H1) mid-tile and (t+1,H0) at tile end, each
//   with exactly 2 newer half-stages in flight -> vmcnt(2*loads_per_half).

template<int K, bool OUT_BF16>
__device__ __forceinline__ void gemm_single_body(
    const bf16* __restrict__ A, int lda,
    const bf16* __restrict__ Bw, const float* __restrict__ bias,
    void* __restrict__ Out, int ldo, int ocol0,
    bf16* sm, int m0, int n0)
{
    int tid = threadIdx.x, lane = tid & 63, w = tid >> 6;
    int wr = w >> 1, wc = w & 1;
    const bf16* Ab = A + (size_t)m0 * lda;
    const bf16* Bb = Bw + (size_t)n0 * K;
    int frow = lane & 15, sl = lane >> 4;
    f32x4 acc[4][2] = {};
    // buffer: AH0 0, AH1 4096, BH0 8192, BH1 10240; stride 12288
    bf16 *buf0 = sm, *buf1 = sm + 12288;

    auto stageH = [&](bf16* p, int u, int h) {    // 3 loads/thread
        stage_half<128>(Ab + u * 64 + h * 32, lda, p + h * 4096, tid);
        stage_half<64>(Bb + u * 64 + h * 32, K, p + 8192 + h * 2048, tid);
    };
    auto rdA = [&](bf16* p, int h, bf16x8 (&af)[4]) {
#pragma unroll
        for (int mf = 0; mf < 4; ++mf)
            af[mf] = frd32(p + h * 4096, wr * 64 + mf * 16 + frow, sl);
    };
    auto rdB = [&](bf16* p, int h, bf16x8 (&bfr)[2]) {
#pragma unroll
        for (int nf = 0; nf < 2; ++nf)
            bfr[nf] = frd32(p + 8192 + h * 2048, wc * 32 + nf * 16 + frow, sl);
    };
    auto mm = [&](bf16x8 (&af)[4], bf16x8 (&bfr)[2]) {
        __builtin_amdgcn_s_setprio(1);
#pragma unroll
        for (int mf = 0; mf < 4; ++mf)
#pragma unroll
            for (int nf = 0; nf < 2; ++nf)
                acc[mf][nf] = __builtin_amdgcn_mfma_f32_16x16x32_bf16(af[mf], bfr[nf], acc[mf][nf], 0, 0, 0);
        __builtin_amdgcn_s_setprio(0);
    };

    // mode: 0 steady, 1 = NT-2, 2 = NT-1
    auto tileS = [&](bf16* b, bf16* nb, int t, int mode) {
        bf16x8 af[4], bfr[2];
        // Phase 1 (ks0)
        if (mode <= 1) stageH(nb, t + 1, 1);
        rdA(b, 0, af); rdB(b, 0, bfr);
        if (mode <= 1) wait_vm<6>(); else wait_vm<0>();   // guard (t,H1)
        __builtin_amdgcn_s_barrier();
        lgkm_fence();
        mm(af, bfr);
        __builtin_amdgcn_s_barrier();
        // Phase 2 (ks1)
        if (mode == 0) stageH(b, t + 2, 0);
        rdA(b, 1, af); rdB(b, 1, bfr);
        if (mode == 0) wait_vm<6>(); else if (mode == 1) wait_vm<3>(); // guard (t+1,H0)
        __builtin_amdgcn_s_barrier();
        lgkm_fence();
        mm(af, bfr);
        __builtin_amdgcn_s_barrier();
    };

    constexpr int NT = K / 64;   // >= 4
    stageH(buf0, 0, 0); stageH(buf0, 0, 1); stageH(buf1, 1, 0);
    wait_vm<6>();                 // drain (0,H0)
    __builtin_amdgcn_s_barrier();
    int t = 0;
    for (; t + 2 < NT; ++t) {
        bf16 *b = (t & 1) ? buf1 : buf0, *nb = (t & 1) ? buf0 : buf1;
        tileS(b, nb, t, 0);
    }
    { bf16 *b = (t & 1) ? buf1 : buf0, *nb = (t & 1) ? buf0 : buf1; tileS(b, nb, t, 1); ++t; }
    { bf16 *b = (t & 1) ? buf1 : buf0, *nb = (t & 1) ? buf0 : buf1; tileS(b, nb, t, 2); }

    int crow = (lane >> 4) * 4;
    int ccol = lane & 15;
#pragma unroll
    for (int mf = 0; mf < 4; ++mf) {
#pragma unroll
        for (int nf = 0; nf < 2; ++nf) {
            int col = n0 + wc * 32 + nf * 16 + ccol;
            float bv = bias[col];
#pragma unroll
            for (int r2 = 0; r2 < 4; ++r2) {
                int row = m0 + wr * 64 + mf * 16 + crow + r2;
                float v = selu_f(acc[mf][nf][r2] + bv);
                if constexpr (OUT_BF16)
                    ((bf16*)Out)[(size_t)row * ldo + ocol0 + col] = (bf16)v;
                else
                    ((float*)Out)[(size_t)row * ldo + ocol0 + col] = v;
            }
        }
    }
}

template<int K>
__device__ __forceinline__ void gemm_dual_body(
    const bf16* __restrict__ Xp, const bf16* __restrict__ Wl,
    const float* __restrict__ bias, bf16* __restrict__ Y,
    bf16* sm, int m0, int n0)
{
    int tid = threadIdx.x, lane = tid & 63, w = tid >> 6;
    int wr = w >> 1, wc = w & 1;
    const bf16* AL = Xp + (size_t)m0 * LDXP;         // bins 0..6
    const bf16* AR = AL + 3072;                      // bins 6..12
    const bf16* Bb = Wl + (size_t)n0 * K;
    int frow = lane & 15, sl = lane >> 4;
    f32x4 accL[4][2] = {}, accR[4][2] = {};
    // buffer: LH0 0, LH1 4096, RH0 8192, RH1 12288, BH0 16384, BH1 18432; stride 20480
    bf16 *buf0 = sm, *buf1 = sm + 20480;

    auto stageH = [&](bf16* p, int u, int h) {    // 5 loads/thread
        stage_half<128>(AL + u * 64 + h * 32, LDXP, p + h * 4096, tid);
        stage_half<128>(AR + u * 64 + h * 32, LDXP, p + 8192 + h * 4096, tid);
        stage_half<64>(Bb + u * 64 + h * 32, K, p + 16384 + h * 2048, tid);
    };
    auto rdL = [&](bf16* p, int h, bf16x8 (&af)[4]) {
#pragma unroll
        for (int mf = 0; mf < 4; ++mf)
            af[mf] = frd32(p + h * 4096, wr * 64 + mf * 16 + frow, sl);
    };
    auto rdR = [&](bf16* p, int h, bf16x8 (&af)[4]) {
#pragma unroll
        for (int mf = 0; mf < 4; ++mf)
            af[mf] = frd32(p + 8192 + h * 4096, wr * 64 + mf * 16 + frow, sl);
    };
    auto rdB = [&](bf16* p, int h, bf16x8 (&bfr)[2]) {
#pragma unroll
        for (int nf = 0; nf < 2; ++nf)
            bfr[nf] = frd32(p + 16384 + h * 2048, wc * 32 + nf * 16 + frow, sl);
    };
    auto mm = [&](bf16x8 (&af)[4], bf16x8 (&bfr)[2], f32x4 (&ac)[4][2]) {
        __builtin_amdgcn_s_setprio(1);
#pragma unroll
        for (int mf = 0; mf < 4; ++mf)
#pragma unroll
            for (int nf = 0; nf < 2; ++nf)
                ac[mf][nf] = __builtin_amdgcn_mfma_f32_16x16x32_bf16(af[mf], bfr[nf], ac[mf][nf], 0, 0, 0);
        __builtin_amdgcn_s_setprio(0);
    };

    // 4 phases/K-tile: (L,ks0) (R,ks0) (L,ks1) (R,ks1); B frags reused L->R.
    auto tileD = [&](bf16* b, bf16* nb, int t, int mode) {
        bf16x8 af[4], bfr[2];
        // Phase 1
        if (mode <= 1) stageH(nb, t + 1, 1);
        rdL(b, 0, af); rdB(b, 0, bfr);
        __builtin_amdgcn_s_barrier();
        lgkm_fence();
        mm(af, bfr, accL);
        __builtin_amdgcn_s_barrier();
        // Phase 2
        rdR(b, 0, af);
        if (mode <= 1) wait_vm<10>(); else wait_vm<0>();  // guard (t,H1)
        __builtin_amdgcn_s_barrier();
        lgkm_fence();
        mm(af, bfr, accR);
        __builtin_amdgcn_s_barrier();
        // Phase 3
        if (mode == 0) stageH(b, t + 2, 0);
        rdL(b, 1, af); rdB(b, 1, bfr);
        __builtin_amdgcn_s_barrier();
        lgkm_fence();
        mm(af, bfr, accL);
        __builtin_amdgcn_s_barrier();
        // Phase 4
        rdR(b, 1, af);
        if (mode == 0) wait_vm<10>(); else if (mode == 1) wait_vm<5>(); // guard (t+1,H0)
        __builtin_amdgcn_s_barrier();
        lgkm_fence();
        mm(af, bfr, accR);
        __builtin_amdgcn_s_barrier();
    };

    constexpr int NT = K / 64;   // 56
    stageH(buf0, 0, 0); stageH(buf0, 0, 1); stageH(buf1, 1, 0);
    wait_vm<10>();               // drain (0,H0)
    __builtin_amdgcn_s_barrier();
    int t = 0;
    for (; t + 2 < NT; ++t) {
        bf16 *b = (t & 1) ? buf1 : buf0, *nb = (t & 1) ? buf0 : buf1;
        tileD(b, nb, t, 0);
    }
    { bf16 *b = (t & 1) ? buf1 : buf0, *nb = (t & 1) ? buf0 : buf1; tileD(b, nb, t, 1); ++t; }
    { bf16 *b = (t & 1) ? buf1 : buf0, *nb = (t & 1) ? buf0 : buf1; tileD(b, nb, t, 2); }

    int crow = (lane >> 4) * 4;
    int ccol = lane & 15;
#pragma unroll
    for (int mf = 0; mf < 4; ++mf) {
#pragma unroll
        for (int nf = 0; nf < 2; ++nf) {
            int col = n0 + wc * 32 + nf * 16 + ccol;
            float bv = bias[col];
#pragma unroll
            for (int r2 = 0; r2 < 4; ++r2) {
                int row = m0 + wr * 64 + mf * 16 + crow + r2;
                float vL = selu_f(accL[mf][nf][r2] + bv);
                float vR = selu_f(accR[mf][nf][r2] + bv);
                Y[(size_t)row * 1024 + col] = (bf16)(vR - vL);
            }
        }
    }
}

// ---------------- GEMM kernels ----------------
// Linear m-major mapping (measured best).  Dual: bids 0..255 (m=bid&31,
// n=bid>>5); inner: 256..511.  LDS 80KB -> 2 blocks/CU exact.
__global__ __launch_bounds__(256) void wide_gemm(
    const bf16* __restrict__ Xp, const bf16* __restrict__ Wl,
    const float* __restrict__ bl, const bf16* __restrict__ Wi,
    const float* __restrict__ bi, bf16* __restrict__ Y)
{
    __shared__ bf16 sm[40960];  // 80 KB
    int bid = blockIdx.x;
    if (bid < 256) {
        gemm_dual_body<3584>(Xp, Wl, bl, Y, sm, (bid & 31) * 128, (bid >> 5) * 64);
    } else {
        int b2 = bid - 256;
        gemm_single_body<4608, true>(Xp + 1024, LDXP, Wi, bi, (void*)Y, 1024, 512,
                                     sm, (b2 & 31) * 128, (b2 >> 5) * 64);
    }
}

__global__ __launch_bounds__(256) void final_gemm(
    const bf16* __restrict__ Y, const bf16* __restrict__ Wr,
    const float* __restrict__ br, float* __restrict__ out)
{
    __shared__ bf16 sm[24576];  // 48 KB
    int bid = blockIdx.x;
    gemm_single_body<1024, false>(Y, 1024, Wr, br, (void*)out, 512, 0,
                                  sm, (bid & 31) * 128, (bid >> 5) * 64);
}

// ---------------- launch ----------------
extern "C" void kernel_launch(void* const* d_in, const int* in_sizes, int n_in,
                              void* d_out, int out_size, void* d_ws, size_t ws_size,
                              hipStream_t stream) {
    const float* feats   = (const float*)d_in[0];
    const float* rois    = (const float*)d_in[3];
    const float* W_left  = (const float*)d_in[6];
    const float* b_left  = (const float*)d_in[7];
    const float* W_inner = (const float*)d_in[8];
    const float* b_inner = (const float*)d_in[9];
    const float* W_roi   = (const float*)d_in[10];
    const float* b_roi   = (const float*)d_in[11];
    float* out = (float*)d_out;

    bf16* wsb = (bf16*)d_ws;
    constexpr size_t XP_ELEMS = (size_t)MM * LDXP;
    constexpr size_t WL_ELEMS = (size_t)512 * 3584;
    constexpr size_t WI_ELEMS = (size_t)512 * 4608;
    constexpr size_t WR_ELEMS = (size_t)512 * 1024;
    bf16* Xp = wsb;
    bf16* Wl = Xp + XP_ELEMS;
    bf16* Wi = Wl + WL_ELEMS;
    bf16* Wr = Wi + WI_ELEMS;
    bf16* Y  = Wr + WR_ELEMS;   // [M][1024]

    prep_all<<<5632, 256, 0, stream>>>(feats, rois, W_left, W_inner, W_roi,
                                       Xp, Wl, Wi, Wr);
    wide_gemm<<<512, 256, 0, stream>>>(Xp, Wl, b_left, Wi, b_inner, Y);
    final_gemm<<<256, 256, 0, stream>>>(Y, Wr, b_roi, out);
}

// Round 10
// 112.214 us; speedup vs baseline: 1.1415x; 1.1415x over previous
//
#include <hip/hip_runtime.h>
#include <hip/hip_bf16.h>
#include <cstdint>
#include <cmath>

#define BB 4
#define TT 2048
#define DD 512
#define RR 1024
#define MM (BB*RR)       // 4096
#define NBINS 13
#define LDXP (NBINS*DD)  // 6656

typedef __bf16 bf16;
typedef bf16 bf16x8 __attribute__((ext_vector_type(8)));
typedef float f32x4 __attribute__((ext_vector_type(4)));

__device__ __forceinline__ float selu_f(float x) {
    const float sc = 1.0507009873554805f;
    const float aa = 1.6732632423543772f;
    return x > 0.0f ? sc * x : sc * aa * (expf(x) - 1.0f);
}

__device__ __forceinline__ void gload_lds16(const bf16* g, bf16* l) {
    __builtin_amdgcn_global_load_lds(
        (const __attribute__((address_space(1))) void*)g,
        (__attribute__((address_space(3))) void*)l, 16, 0, 0);
}

template<int N>
__device__ __forceinline__ void wait_vm() {
    if constexpr (N == 0)      asm volatile("s_waitcnt vmcnt(0)" ::: "memory");
    else if constexpr (N == 2) asm volatile("s_waitcnt vmcnt(2)" ::: "memory");
    else if constexpr (N == 3) asm volatile("s_waitcnt vmcnt(3)" ::: "memory");
}

__device__ __forceinline__ void lgkm_fence() {
    asm volatile("s_waitcnt lgkmcnt(0)" ::: "memory");
    __builtin_amdgcn_sched_barrier(0);
}

// Stage a [ROWS][32] bf16 half-tile into LDS, swizzled: physical 16B slot p of
// row r holds logical slot p ^ ((r>>1)&3).  LDS dest linear (global_load_lds
// writes wave-base + lane*16); source address carries the permutation.
template<int ROWS, int NTHR>
__device__ __forceinline__ void stage_half(const bf16* __restrict__ src, int lda,
                                           bf16* dst, int tid) {
#pragma unroll
    for (int it = 0; it < (ROWS * 4) / NTHR; ++it) {
        int idx = it * NTHR + tid;
        int row = idx >> 2;                               // 4 slots of 16B per 64B row
        int col = ((idx & 3) ^ ((row >> 1) & 3)) * 8;
        bf16* wavebase = dst + (idx & ~63) * 8;           // wave-uniform base
        gload_lds16(src + (size_t)row * lda + col, wavebase);
    }
}

// Fragment read with the matching XOR (2-way bank alias = free).
__device__ __forceinline__ bf16x8 frd32(const bf16* half, int row, int sl) {
    int p = sl ^ ((row >> 1) & 3);
    return *(const bf16x8*)(half + row * 32 + p * 8);
}

// ---------------- fused prep: pool + weight transforms ----------------
template<int NB_, int KT>
__device__ __forceinline__ void w_row_body(const float* __restrict__ Wsrc,
                                           bf16* __restrict__ Wdst,
                                           float* ld, int n, int tid) {
    const float* src = Wsrc + (size_t)n * KT;
    for (int i = tid; i < KT; i += 256) ld[i] = src[i];
    __syncthreads();
    bf16* dst = Wdst + (size_t)n * KT;
    for (int i = tid; i < KT; i += 256) {
        int bin = i >> 9, d = i & 511;
        dst[i] = (bf16)ld[d * NB_ + bin];
    }
}

// 256 threads: 64 threads x 8 d-values cover D=512; 4 bins concurrently.
__device__ __forceinline__ void pool_body(const float* __restrict__ feats,
                                          const float* __restrict__ rois,
                                          bf16* __restrict__ Xp, int m, int tid) {
    int b = m >> 10;
    float s = rois[2 * m];
    float e = rois[2 * m + 1];
    float ext = 0.2f * (e - s);
    int dd = (tid & 63) * 8;
    int j0 = tid >> 6;
    const float* fb = feats + (size_t)b * TT * DD + dd;
    bf16* orow = Xp + (size_t)m * LDXP + dd;
#pragma unroll
    for (int jj = 0; jj < 4; ++jj) {
        int j = j0 + jj * 4;
        if (j >= NBINS) break;
        float pos;
        if (j < 2)       pos = (s - ext) + ((float)j + 0.5f) * ext;
        else if (j < 11) pos = s + (((float)(j - 2) + 0.5f) * (1.0f / 9.0f)) * (e - s);
        else             pos = (e - ext) + ((float)(j - 11) + 0.5f) * ext;
        pos = fminf(fmaxf(pos, 0.0f), (float)(TT - 1));
        float fl = floorf(pos);
        int lo = (int)fl;
        int hi = lo + 1; if (hi > TT - 1) hi = TT - 1;
        float w = pos - fl;
        const float* rlo = fb + (size_t)lo * DD;
        const float* rhi = fb + (size_t)hi * DD;
        float4 l0 = *(const float4*)(rlo);
        float4 l1 = *(const float4*)(rlo + 4);
        float4 h0 = *(const float4*)(rhi);
        float4 h1 = *(const float4*)(rhi + 4);
        bf16x8 o;
        o[0] = (bf16)((1.0f - w) * l0.x + w * h0.x);
        o[1] = (bf16)((1.0f - w) * l0.y + w * h0.y);
        o[2] = (bf16)((1.0f - w) * l0.z + w * h0.z);
        o[3] = (bf16)((1.0f - w) * l0.w + w * h0.w);
        o[4] = (bf16)((1.0f - w) * l1.x + w * h1.x);
        o[5] = (bf16)((1.0f - w) * l1.y + w * h1.y);
        o[6] = (bf16)((1.0f - w) * l1.z + w * h1.z);
        o[7] = (bf16)((1.0f - w) * l1.w + w * h1.w);
        *(bf16x8*)(orow + j * DD) = o;
    }
}

__global__ __launch_bounds__(256) void prep_all(
    const float* __restrict__ feats, const float* __restrict__ rois,
    const float* __restrict__ W_left, const float* __restrict__ W_inner,
    const float* __restrict__ W_roi,
    bf16* __restrict__ Xp, bf16* __restrict__ Wl, bf16* __restrict__ Wi,
    bf16* __restrict__ Wr)
{
    __shared__ float ld[4608];
    int bid = blockIdx.x, tid = threadIdx.x;
    if (bid < 4096) {
        pool_body(feats, rois, Xp, bid, tid);
    } else if (bid < 4608) {
        w_row_body<7, 3584>(W_left, Wl, ld, bid - 4096, tid);
    } else if (bid < 5120) {
        w_row_body<9, 4608>(W_inner, Wi, ld, bid - 4608, tid);
    } else {
        int i0 = (bid - 5120) * 1024 + tid * 4;
        float4 v = *(const float4*)(W_roi + i0);
        bf16* d = Wr + i0;
        d[0] = (bf16)v.x; d[1] = (bf16)v.y; d[2] = (bf16)v.z; d[3] = (bf16)v.w;
    }
}

// ---------------- GEMM bodies ----------------
// 512 threads = 8 waves (4M x 2N), BM=128, BN=128, BK=64 in 2 halves.
// Wave tile 32x64 (mf=2, nf=4) -- minimizes LDS frag-read duplication.
// Single LDS buffer; per phase: counted vmcnt -> barrier -> ds_read frags ->
// lgkmcnt(0)+sched_barrier -> barrier -> stage same half of t+1 (overwrite,
// legal past barrier) -> setprio MFMA.  vmcnt induction (loads/half-stage =
// Ld): entering P1(t): outstanding = H0(t)+H1(t) = 2Ld -> vm(Ld) retires
// H0(t); entering P2(t): H1(t)+H0(t+1) -> vm(Ld) retires H1(t); last P2:
// only H1 left -> vm(0).  Never drains mid-loop.

template<int K, bool OUT_BF16>
__device__ __forceinline__ void gemm_single_body(
    const bf16* __restrict__ A, int lda,
    const bf16* __restrict__ Bw, const float* __restrict__ bias,
    void* __restrict__ Out, int ldo, int ocol0,
    bf16* sm, int m0, int n0)
{
    int tid = threadIdx.x, lane = tid & 63, w = tid >> 6;
    int wr = w >> 1, wc = w & 1;           // 4M x 2N
    const bf16* Ab = A + (size_t)m0 * lda;
    const bf16* Bb = Bw + (size_t)n0 * K;
    int frow = lane & 15, sl = lane >> 4;
    f32x4 acc[2][4] = {};

    auto stageH = [&](int t, int h) {      // 2 loads/thread
        stage_half<128, 512>(Ab + t * 64 + h * 32, lda, sm + h * 4096, tid);
        stage_half<128, 512>(Bb + t * 64 + h * 32, K, sm + 8192 + h * 4096, tid);
    };
    auto phase = [&](int t, int h, bool dostage, bool last) {
        if (last) wait_vm<0>(); else wait_vm<2>();
        __builtin_amdgcn_s_barrier();
        bf16x8 af[2], bfr[4];
#pragma unroll
        for (int mf = 0; mf < 2; ++mf)
            af[mf] = frd32(sm + h * 4096, wr * 32 + mf * 16 + frow, sl);
#pragma unroll
        for (int nf = 0; nf < 4; ++nf)
            bfr[nf] = frd32(sm + 8192 + h * 4096, wc * 64 + nf * 16 + frow, sl);
        lgkm_fence();
        __builtin_amdgcn_s_barrier();
        if (dostage) stageH(t + 1, h);
        __builtin_amdgcn_sched_barrier(0);
        __builtin_amdgcn_s_setprio(1);
#pragma unroll
        for (int mf = 0; mf < 2; ++mf)
#pragma unroll
            for (int nf = 0; nf < 4; ++nf)
                acc[mf][nf] = __builtin_amdgcn_mfma_f32_16x16x32_bf16(af[mf], bfr[nf], acc[mf][nf], 0, 0, 0);
        __builtin_amdgcn_s_setprio(0);
    };

    constexpr int NT = K / 64;
    stageH(0, 0); stageH(0, 1);
    for (int t = 0; t < NT; ++t) {
        bool more = (t + 1 < NT);
        phase(t, 0, more, false);
        phase(t, 1, more, !more);
    }

    int crow = (lane >> 4) * 4;
    int ccol = lane & 15;
#pragma unroll
    for (int mf = 0; mf < 2; ++mf) {
#pragma unroll
        for (int nf = 0; nf < 4; ++nf) {
            int col = n0 + wc * 64 + nf * 16 + ccol;
            float bv = bias[col];
#pragma unroll
            for (int r2 = 0; r2 < 4; ++r2) {
                int row = m0 + wr * 32 + mf * 16 + crow + r2;
                float v = selu_f(acc[mf][nf][r2] + bv);
                if constexpr (OUT_BF16)
                    ((bf16*)Out)[(size_t)row * ldo + ocol0 + col] = (bf16)v;
                else
                    ((float*)Out)[(size_t)row * ldo + ocol0 + col] = v;
            }
        }
    }
}

template<int K>
__device__ __forceinline__ void gemm_dual_body(
    const bf16* __restrict__ Xp, const bf16* __restrict__ Wl,
    const float* __restrict__ bias, bf16* __restrict__ Y,
    bf16* sm, int m0, int n0)
{
    int tid = threadIdx.x, lane = tid & 63, w = tid >> 6;
    int wr = w >> 1, wc = w & 1;           // 4M x 2N
    const bf16* AL = Xp + (size_t)m0 * LDXP;         // bins 0..6
    const bf16* AR = AL + 3072;                      // bins 6..12
    const bf16* Bb = Wl + (size_t)n0 * K;
    int frow = lane & 15, sl = lane >> 4;
    f32x4 accL[2][4] = {}, accR[2][4] = {};
    // LDS: LH h*4096 | RH 8192+h*4096 | BH 16384+h*4096  (24576 elems = 48KB)

    auto stageH = [&](int t, int h) {      // 3 loads/thread
        stage_half<128, 512>(AL + t * 64 + h * 32, LDXP, sm + h * 4096, tid);
        stage_half<128, 512>(AR + t * 64 + h * 32, LDXP, sm + 8192 + h * 4096, tid);
        stage_half<128, 512>(Bb + t * 64 + h * 32, K, sm + 16384 + h * 4096, tid);
    };
    auto phase = [&](int t, int h, bool dostage, bool last) {
        if (last) wait_vm<0>(); else wait_vm<3>();
        __builtin_amdgcn_s_barrier();
        bf16x8 afL[2], afR[2], bfr[4];
#pragma unroll
        for (int mf = 0; mf < 2; ++mf) {
            afL[mf] = frd32(sm + h * 4096, wr * 32 + mf * 16 + frow, sl);
            afR[mf] = frd32(sm + 8192 + h * 4096, wr * 32 + mf * 16 + frow, sl);
        }
#pragma unroll
        for (int nf = 0; nf < 4; ++nf)
            bfr[nf] = frd32(sm + 16384 + h * 4096, wc * 64 + nf * 16 + frow, sl);
        lgkm_fence();
        __builtin_amdgcn_s_barrier();
        if (dostage) stageH(t + 1, h);
        __builtin_amdgcn_sched_barrier(0);
        __builtin_amdgcn_s_setprio(1);
#pragma unroll
        for (int mf = 0; mf < 2; ++mf)
#pragma unroll
            for (int nf = 0; nf < 4; ++nf) {
                accL[mf][nf] = __builtin_amdgcn_mfma_f32_16x16x32_bf16(afL[mf], bfr[nf], accL[mf][nf], 0, 0, 0);
                accR[mf][nf] = __builtin_amdgcn_mfma_f32_16x16x32_bf16(afR[mf], bfr[nf], accR[mf][nf], 0, 0, 0);
            }
        __builtin_amdgcn_s_setprio(0);
    };

    constexpr int NT = K / 64;   // 56
    stageH(0, 0); stageH(0, 1);
    for (int t = 0; t < NT; ++t) {
        bool more = (t + 1 < NT);
        phase(t, 0, more, false);
        phase(t, 1, more, !more);
    }

    int crow = (lane >> 4) * 4;
    int ccol = lane & 15;
#pragma unroll
    for (int mf = 0; mf < 2; ++mf) {
#pragma unroll
        for (int nf = 0; nf < 4; ++nf) {
            int col = n0 + wc * 64 + nf * 16 + ccol;
            float bv = bias[col];
#pragma unroll
            for (int r2 = 0; r2 < 4; ++r2) {
                int row = m0 + wr * 32 + mf * 16 + crow + r2;
                float vL = selu_f(accL[mf][nf][r2] + bv);
                float vR = selu_f(accR[mf][nf][r2] + bv);
                Y[(size_t)row * 1024 + col] = (bf16)(vR - vL);
            }
        }
    }
}

// ---------------- GEMM kernels ----------------
// grid 256 = 128 dual + 128 inner = exactly 1 block/CU, 8 waves each
// (2 waves/SIMD -- the phase-overhead cover r9 lacked).  Linear m-major.
__global__ __launch_bounds__(512) void wide_gemm(
    const bf16* __restrict__ Xp, const bf16* __restrict__ Wl,
    const float* __restrict__ bl, const bf16* __restrict__ Wi,
    const float* __restrict__ bi, bf16* __restrict__ Y)
{
    __shared__ bf16 sm[24576];  // 48 KB (dual); inner uses 32 KB of it
    int bid = blockIdx.x;
    if (bid < 128) {
        gemm_dual_body<3584>(Xp, Wl, bl, Y, sm, (bid & 31) * 128, (bid >> 5) * 128);
    } else {
        int b2 = bid - 128;
        gemm_single_body<4608, true>(Xp + 1024, LDXP, Wi, bi, (void*)Y, 1024, 512,
                                     sm, (b2 & 31) * 128, (b2 >> 5) * 128);
    }
}

__global__ __launch_bounds__(512) void final_gemm(
    const bf16* __restrict__ Y, const bf16* __restrict__ Wr,
    const float* __restrict__ br, float* __restrict__ out)
{
    __shared__ bf16 sm[16384];  // 32 KB
    int bid = blockIdx.x;
    gemm_single_body<1024, false>(Y, 1024, Wr, br, (void*)out, 512, 0,
                                  sm, (bid & 31) * 128, (bid >> 5) * 128);
}

// ---------------- launch ----------------
extern "C" void kernel_launch(void* const* d_in, const int* in_sizes, int n_in,
                              void* d_out, int out_size, void* d_ws, size_t ws_size,
                              hipStream_t stream) {
    const float* feats   = (const float*)d_in[0];
    const float* rois    = (const float*)d_in[3];
    const float* W_left  = (const float*)d_in[6];
    const float* b_left  = (const float*)d_in[7];
    const float* W_inner = (const float*)d_in[8];
    const float* b_inner = (const float*)d_in[9];
    const float* W_roi   = (const float*)d_in[10];
    const float* b_roi   = (const float*)d_in[11];
    float* out = (float*)d_out;

    bf16* wsb = (bf16*)d_ws;
    constexpr size_t XP_ELEMS = (size_t)MM * LDXP;
    constexpr size_t WL_ELEMS = (size_t)512 * 3584;
    constexpr size_t WI_ELEMS = (size_t)512 * 4608;
    constexpr size_t WR_ELEMS = (size_t)512 * 1024;
    bf16* Xp = wsb;
    bf16* Wl = Xp + XP_ELEMS;
    bf16* Wi = Wl + WL_ELEMS;
    bf16* Wr = Wi + WI_ELEMS;
    bf16* Y  = Wr + WR_ELEMS;   // [M][1024]

    prep_all<<<5632, 256, 0, stream>>>(feats, rois, W_left, W_inner, W_roi,
                                       Xp, Wl, Wi, Wr);
    wide_gemm<<<256, 512, 0, stream>>>(Xp, Wl, b_left, Wi, b_inner, Y);
    final_gemm<<<128, 512, 0, stream>>>(Y, Wr, b_roi, out);
}

// Round 11
// 101.732 us; speedup vs baseline: 1.2591x; 1.1030x over previous
//
#include <hip/hip_runtime.h>
#include <hip/hip_bf16.h>
#include <cstdint>
#include <cmath>

#define BB 4
#define TT 2048
#define DD 512
#define RR 1024
#define MM (BB*RR)       // 4096
#define NBINS 13
#define LDXP (NBINS*DD)  // 6656

typedef __bf16 bf16;
typedef bf16 bf16x8 __attribute__((ext_vector_type(8)));
typedef float f32x4 __attribute__((ext_vector_type(4)));

__device__ __forceinline__ float selu_f(float x) {
    const float sc = 1.0507009873554805f;
    const float aa = 1.6732632423543772f;
    return x > 0.0f ? sc * x : sc * aa * (expf(x) - 1.0f);
}

__device__ __forceinline__ void gload_lds16(const bf16* g, bf16* l) {
    __builtin_amdgcn_global_load_lds(
        (const __attribute__((address_space(1))) void*)g,
        (__attribute__((address_space(3))) void*)l, 16, 0, 0);
}

template<int N>
__device__ __forceinline__ void wait_vm() {
    if constexpr (N == 0)      asm volatile("s_waitcnt vmcnt(0)" ::: "memory");
    else if constexpr (N == 6) asm volatile("s_waitcnt vmcnt(6)" ::: "memory");
    else if constexpr (N == 8) asm volatile("s_waitcnt vmcnt(8)" ::: "memory");
}

// Stage a [ROWS][64] bf16 tile into LDS, XOR-swizzled: physical 16B slot p of
// row r holds logical slot p ^ (r&7).  LDS dest stays linear (global_load_lds
// writes wave-base + lane*16); the source address carries the permutation.
template<int ROWS>
__device__ __forceinline__ void stage_tile64(const bf16* __restrict__ src, int lda,
                                             bf16* tile, int tid) {
#pragma unroll
    for (int it = 0; it < ROWS / 32; ++it) {     // 256 threads cover 32 rows/iter
        int idx = it * 256 + tid;
        int row = idx >> 3;                       // 8 slots of 16B per 128B row
        int col = ((idx & 7) ^ (row & 7)) * 8;
        bf16* wavebase = tile + (idx & ~63) * 8;  // wave-uniform base
        gload_lds16(src + (size_t)row * lda + col, wavebase);
    }
}

// Fragment read with the matching XOR (2-way bank alias = free).
__device__ __forceinline__ bf16x8 frd64(const bf16* tile, int row, int s) {
    int p = s ^ (row & 7);
    return *(const bf16x8*)(tile + row * 64 + p * 8);
}

// ---------------- fused prep: pool + weight transforms ----------------
template<int NB_, int KT>
__device__ __forceinline__ void w_row_body(const float* __restrict__ Wsrc,
                                           bf16* __restrict__ Wdst,
                                           float* ld, int n, int tid) {
    const float* src = Wsrc + (size_t)n * KT;
    for (int i = tid; i < KT; i += 256) ld[i] = src[i];
    __syncthreads();
    bf16* dst = Wdst + (size_t)n * KT;
    for (int i = tid; i < KT; i += 256) {
        int bin = i >> 9, d = i & 511;
        dst[i] = (bf16)ld[d * NB_ + bin];
    }
}

// 256 threads: 64 threads x 8 d-values cover D=512; 4 bins concurrently.
__device__ __forceinline__ void pool_body(const float* __restrict__ feats,
                                          const float* __restrict__ rois,
                                          bf16* __restrict__ Xp, int m, int tid) {
    int b = m >> 10;
    float s = rois[2 * m];
    float e = rois[2 * m + 1];
    float ext = 0.2f * (e - s);
    int dd = (tid & 63) * 8;
    int j0 = tid >> 6;
    const float* fb = feats + (size_t)b * TT * DD + dd;
    bf16* orow = Xp + (size_t)m * LDXP + dd;
#pragma unroll
    for (int jj = 0; jj < 4; ++jj) {
        int j = j0 + jj * 4;
        if (j >= NBINS) break;
        float pos;
        if (j < 2)       pos = (s - ext) + ((float)j + 0.5f) * ext;
        else if (j < 11) pos = s + (((float)(j - 2) + 0.5f) * (1.0f / 9.0f)) * (e - s);
        else             pos = (e - ext) + ((float)(j - 11) + 0.5f) * ext;
        pos = fminf(fmaxf(pos, 0.0f), (float)(TT - 1));
        float fl = floorf(pos);
        int lo = (int)fl;
        int hi = lo + 1; if (hi > TT - 1) hi = TT - 1;
        float w = pos - fl;
        const float* rlo = fb + (size_t)lo * DD;
        const float* rhi = fb + (size_t)hi * DD;
        float4 l0 = *(const float4*)(rlo);
        float4 l1 = *(const float4*)(rlo + 4);
        float4 h0 = *(const float4*)(rhi);
        float4 h1 = *(const float4*)(rhi + 4);
        bf16x8 o;
        o[0] = (bf16)((1.0f - w) * l0.x + w * h0.x);
        o[1] = (bf16)((1.0f - w) * l0.y + w * h0.y);
        o[2] = (bf16)((1.0f - w) * l0.z + w * h0.z);
        o[3] = (bf16)((1.0f - w) * l0.w + w * h0.w);
        o[4] = (bf16)((1.0f - w) * l1.x + w * h1.x);
        o[5] = (bf16)((1.0f - w) * l1.y + w * h1.y);
        o[6] = (bf16)((1.0f - w) * l1.z + w * h1.z);
        o[7] = (bf16)((1.0f - w) * l1.w + w * h1.w);
        *(bf16x8*)(orow + j * DD) = o;
    }
}

__global__ __launch_bounds__(256) void prep_all(
    const float* __restrict__ feats, const float* __restrict__ rois,
    const float* __restrict__ W_left, const float* __restrict__ W_inner,
    const float* __restrict__ W_roi,
    bf16* __restrict__ Xp, bf16* __restrict__ Wl, bf16* __restrict__ Wi,
    bf16* __restrict__ Wr)
{
    __shared__ float ld[4608];
    int bid = blockIdx.x, tid = threadIdx.x;
    if (bid < 4096) {
        pool_body(feats, rois, Xp, bid, tid);
    } else if (bid < 4608) {
        w_row_body<7, 3584>(W_left, Wl, ld, bid - 4096, tid);
    } else if (bid < 5120) {
        w_row_body<9, 4608>(W_inner, Wi, ld, bid - 4608, tid);
    } else {
        int i0 = (bid - 5120) * 1024 + tid * 4;
        float4 v = *(const float4*)(W_roi + i0);
        bf16* d = Wr + i0;
        d[0] = (bf16)v.x; d[1] = (bf16)v.y; d[2] = (bf16)v.z; d[3] = (bf16)v.w;
    }
}

// ---------------- GEMM bodies (measured-best structure, r5/r6) ----------------
// BM=64, BN=128, BK=64; 256 threads = 4 waves (2x2), wave tile 32x64 (2x4).
// Depth-2 pipeline, two buffers: per step, read ALL fragments of tile t into
// registers, lgkmcnt(0)+barrier, overwrite the SAME buffer with tile t+2
// (write-after-read legal past the barrier), then pure-reg MFMA cluster.
// Exact counted vmcnt: entering step t, outstanding = stage(t)[8/6 loads,
// issued t-2] + stage(t+1)[issued t-1]; vmcnt(loads_per_stage) retires ALL of
// stage(t) and never drains the newer stage.  (r6 shipped 12/10 here -- a
// 4-load race window that happened to pass; 8/6 is the exact guard.)

template<int K, bool OUT_BF16>
__device__ __forceinline__ void gemm_single_body(
    const bf16* __restrict__ A, int lda,
    const bf16* __restrict__ Bw, const float* __restrict__ bias,
    void* __restrict__ Out, int ldo, int ocol0,
    bf16* sm, int m0, int n0)
{
    int tid = threadIdx.x, lane = tid & 63, w = tid >> 6;
    int wr = w >> 1, wc = w & 1;
    const bf16* Ab = A + (size_t)m0 * lda;
    const bf16* Bb = Bw + (size_t)n0 * K;
    int frow = lane & 15, sl = lane >> 4;
    f32x4 acc[2][4] = {};
    bf16 *A0 = sm,         *B0 = sm + 4096;
    bf16 *A1 = sm + 12288, *B1 = sm + 12288 + 4096;

    auto stage = [&](bf16* as, bf16* bs, int t) {   // 6 loads/thread
        stage_tile64<64>(Ab + t * 64, lda, as, tid);
        stage_tile64<128>(Bb + t * 64, K, bs, tid);
    };
    auto step_body = [&](bf16* as, bf16* bs, int t, bool dostage) {
        __builtin_amdgcn_s_barrier();              // tile-t loads landed (all waves)
        bf16x8 af[2][2], bfr[2][4];
#pragma unroll
        for (int ks = 0; ks < 2; ++ks) {
#pragma unroll
            for (int mf = 0; mf < 2; ++mf) af[ks][mf] = frd64(as, wr * 32 + mf * 16 + frow, ks * 4 + sl);
#pragma unroll
            for (int nf = 0; nf < 4; ++nf) bfr[ks][nf] = frd64(bs, wc * 64 + nf * 16 + frow, ks * 4 + sl);
        }
        asm volatile("s_waitcnt lgkmcnt(0)" ::: "memory");
        __builtin_amdgcn_sched_barrier(0);
        __builtin_amdgcn_s_barrier();              // all waves done reading buf
        if (dostage) stage(as, bs, t + 2);         // overwrite with tile t+2
        __builtin_amdgcn_s_setprio(1);
#pragma unroll
        for (int ks = 0; ks < 2; ++ks)
#pragma unroll
            for (int mf = 0; mf < 2; ++mf)
#pragma unroll
                for (int nf = 0; nf < 4; ++nf)
                    acc[mf][nf] = __builtin_amdgcn_mfma_f32_16x16x32_bf16(af[ks][mf], bfr[ks][nf], acc[mf][nf], 0, 0, 0);
        __builtin_amdgcn_s_setprio(0);
    };

    constexpr int NT = K / 64;   // even, >= 4 for all instantiations
    stage(A0, B0, 0);
    stage(A1, B1, 1);
    for (int t = 0; t + 2 < NT; t += 2) {
        wait_vm<6>(); step_body(A0, B0, t, true);
        wait_vm<6>(); step_body(A1, B1, t + 1, true);
    }
    wait_vm<6>(); step_body(A0, B0, NT - 2, false);
    wait_vm<0>(); step_body(A1, B1, NT - 1, false);

    int crow = (lane >> 4) * 4;
    int ccol = lane & 15;
#pragma unroll
    for (int mf = 0; mf < 2; ++mf) {
#pragma unroll
        for (int nf = 0; nf < 4; ++nf) {
            int col = n0 + wc * 64 + nf * 16 + ccol;
            float bv = bias[col];
#pragma unroll
            for (int r2 = 0; r2 < 4; ++r2) {
                int row = m0 + wr * 32 + mf * 16 + crow + r2;
                float v = selu_f(acc[mf][nf][r2] + bv);
                if constexpr (OUT_BF16)
                    ((bf16*)Out)[(size_t)row * ldo + ocol0 + col] = (bf16)v;
                else
                    ((float*)Out)[(size_t)row * ldo + ocol0 + col] = v;
            }
        }
    }
}

template<int K>
__device__ __forceinline__ void gemm_dual_body(
    const bf16* __restrict__ Xp, const bf16* __restrict__ Wl,
    const float* __restrict__ bias, bf16* __restrict__ Y,
    bf16* sm, int m0, int n0)
{
    int tid = threadIdx.x, lane = tid & 63, w = tid >> 6;
    int wr = w >> 1, wc = w & 1;
    const bf16* AL = Xp + (size_t)m0 * LDXP;         // bins 0..6
    const bf16* AR = AL + 3072;                      // bins 6..12
    const bf16* Bb = Wl + (size_t)n0 * K;
    int frow = lane & 15, sl = lane >> 4;
    f32x4 accL[2][4] = {}, accR[2][4] = {};
    bf16 *L0 = sm,         *R0 = sm + 4096,         *B0 = sm + 8192;
    bf16 *L1 = sm + 16384, *R1 = sm + 16384 + 4096, *B1 = sm + 16384 + 8192;

    auto stage = [&](bf16* ls, bf16* rs, bf16* bs, int t) {  // 8 loads/thread
        stage_tile64<64>(AL + t * 64, LDXP, ls, tid);
        stage_tile64<64>(AR + t * 64, LDXP, rs, tid);
        stage_tile64<128>(Bb + t * 64, K, bs, tid);
    };
    auto step_body = [&](bf16* ls, bf16* rs, bf16* bs, int t, bool dostage) {
        __builtin_amdgcn_s_barrier();
        bf16x8 afL[2][2], afR[2][2], bfr[2][4];
#pragma unroll
        for (int ks = 0; ks < 2; ++ks) {
#pragma unroll
            for (int mf = 0; mf < 2; ++mf) {
                afL[ks][mf] = frd64(ls, wr * 32 + mf * 16 + frow, ks * 4 + sl);
                afR[ks][mf] = frd64(rs, wr * 32 + mf * 16 + frow, ks * 4 + sl);
            }
#pragma unroll
            for (int nf = 0; nf < 4; ++nf) bfr[ks][nf] = frd64(bs, wc * 64 + nf * 16 + frow, ks * 4 + sl);
        }
        asm volatile("s_waitcnt lgkmcnt(0)" ::: "memory");
        __builtin_amdgcn_sched_barrier(0);
        __builtin_amdgcn_s_barrier();
        if (dostage) stage(ls, rs, bs, t + 2);
        __builtin_amdgcn_s_setprio(1);
#pragma unroll
        for (int ks = 0; ks < 2; ++ks)
#pragma unroll
            for (int mf = 0; mf < 2; ++mf)
#pragma unroll
                for (int nf = 0; nf < 4; ++nf) {
                    accL[mf][nf] = __builtin_amdgcn_mfma_f32_16x16x32_bf16(afL[ks][mf], bfr[ks][nf], accL[mf][nf], 0, 0, 0);
                    accR[mf][nf] = __builtin_amdgcn_mfma_f32_16x16x32_bf16(afR[ks][mf], bfr[ks][nf], accR[mf][nf], 0, 0, 0);
                }
        __builtin_amdgcn_s_setprio(0);
    };

    constexpr int NT = K / 64;   // 56
    stage(L0, R0, B0, 0);
    stage(L1, R1, B1, 1);
    for (int t = 0; t + 2 < NT; t += 2) {
        wait_vm<8>(); step_body(L0, R0, B0, t, true);
        wait_vm<8>(); step_body(L1, R1, B1, t + 1, true);
    }
    wait_vm<8>(); step_body(L0, R0, B0, NT - 2, false);
    wait_vm<0>(); step_body(L1, R1, B1, NT - 1, false);

    int crow = (lane >> 4) * 4;
    int ccol = lane & 15;
#pragma unroll
    for (int mf = 0; mf < 2; ++mf) {
#pragma unroll
        for (int nf = 0; nf < 4; ++nf) {
            int col = n0 + wc * 64 + nf * 16 + ccol;
            float bv = bias[col];
#pragma unroll
            for (int r2 = 0; r2 < 4; ++r2) {
                int row = m0 + wr * 32 + mf * 16 + crow + r2;
                float vL = selu_f(accL[mf][nf][r2] + bv);
                float vR = selu_f(accR[mf][nf][r2] + bv);
                Y[(size_t)row * 1024 + col] = (bf16)(vR - vL);
            }
        }
    }
}

// ---------------- GEMM kernels ----------------
// Linear m-major mapping (measured best): dual bids 0..255, inner 256..511.
// bid and bid+64 share an XCD -> all 4 n-strips of an m-tile co-locate; each
// CU carries one dual + one inner block (cross-block stall covering).
__global__ __launch_bounds__(256) void wide_gemm(
    const bf16* __restrict__ Xp, const bf16* __restrict__ Wl,
    const float* __restrict__ bl, const bf16* __restrict__ Wi,
    const float* __restrict__ bi, bf16* __restrict__ Y)
{
    __shared__ bf16 sm[32768];  // 64 KB: 2 x (64+64+128)x64
    int bid = blockIdx.x;
    if (bid < 256) {
        gemm_dual_body<3584>(Xp, Wl, bl, Y, sm, (bid & 63) * 64, (bid >> 6) * 128);
    } else {
        int b2 = bid - 256;
        gemm_single_body<4608, true>(Xp + 1024, LDXP, Wi, bi, (void*)Y, 1024, 512,
                                     sm, (b2 & 63) * 64, (b2 >> 6) * 128);
    }
}

__global__ __launch_bounds__(256) void final_gemm(
    const bf16* __restrict__ Y, const bf16* __restrict__ Wr,
    const float* __restrict__ br, float* __restrict__ out)
{
    __shared__ bf16 sm[24576];  // 48 KB
    int bid = blockIdx.x;
    gemm_single_body<1024, false>(Y, 1024, Wr, br, (void*)out, 512, 0,
                                  sm, (bid & 63) * 64, (bid >> 6) * 128);
}

// ---------------- launch ----------------
extern "C" void kernel_launch(void* const* d_in, const int* in_sizes, int n_in,
                              void* d_out, int out_size, void* d_ws, size_t ws_size,
                              hipStream_t stream) {
    const float* feats   = (const float*)d_in[0];
    const float* rois    = (const float*)d_in[3];
    const float* W_left  = (const float*)d_in[6];
    const float* b_left  = (const float*)d_in[7];
    const float* W_inner = (const float*)d_in[8];
    const float* b_inner = (const float*)d_in[9];
    const float* W_roi   = (const float*)d_in[10];
    const float* b_roi   = (const float*)d_in[11];
    float* out = (float*)d_out;

    bf16* wsb = (bf16*)d_ws;
    constexpr size_t XP_ELEMS = (size_t)MM * LDXP;
    constexpr size_t WL_ELEMS = (size_t)512 * 3584;
    constexpr size_t WI_ELEMS = (size_t)512 * 4608;
    constexpr size_t WR_ELEMS = (size_t)512 * 1024;
    bf16* Xp = wsb;
    bf16* Wl = Xp + XP_ELEMS;
    bf16* Wi = Wl + WL_ELEMS;
    bf16* Wr = Wi + WI_ELEMS;
    bf16* Y  = Wr + WR_ELEMS;   // [M][1024]

    prep_all<<<5632, 256, 0, stream>>>(feats, rois, W_left, W_inner, W_roi,
                                       Xp, Wl, Wi, Wr);
    wide_gemm<<<512, 256, 0, stream>>>(Xp, Wl, b_left, Wi, b_inner, Y);
    final_gemm<<<256, 256, 0, stream>>>(Y, Wr, b_roi, out);
}